// Round 4
// baseline (521.970 us; speedup 1.0000x reference)
//
#include <hip/hip_runtime.h>
#include <hip/hip_fp16.h>

#define NPIX 65536
#define WIMG 256
#define HIMG 256
#define TW 16
#define TH 8
#define HSTR 24      // padded halo row stride (halves)
#define HROWS 10
#define HSLOTS 240   // HROWS*HSTR
#define MT_N 15      // m-tiles of 16 over 240 slots

typedef __attribute__((ext_vector_type(8))) _Float16 half8;
typedef __attribute__((ext_vector_type(4))) float f32x4;

__device__ __forceinline__ unsigned int h2u(__half2 h) {
  union { __half2 h; unsigned int u; } c; c.h = h; return c.u;
}
__device__ __forceinline__ __half2 u2h(unsigned int u) {
  union { unsigned int u; __half2 h; } c; c.u = u; return c.h;
}
// xs layout: [px][c] with 16B-block XOR swizzle; returns half-index
__device__ __forceinline__ int xs_idx(int px, int c) {
  return px * 64 + ((((c >> 3) ^ (px & 7)) << 3) | (c & 7));
}
// qs/ks layout: [ch][px 0..127] swizzled; pxblk = px>>3; returns half-index of 8-px block
__device__ __forceinline__ int qk_idx(int ch, int pxblk) {
  return ch * 128 + ((pxblk ^ (ch & 7)) << 3);
}

__global__ void k_zero(float* __restrict__ p, int n) {
  int i = blockIdx.x * 256 + threadIdx.x;
  if (i < n) p[i] = 0.0f;
}

__global__ __launch_bounds__(512, 4)
void k_qkv(const float* __restrict__ x,
           const float* __restrict__ wqkv1, const float* __restrict__ wqkv2,
           const float* __restrict__ wdw1, const float* __restrict__ wdw2,
           __half* __restrict__ vbuf, float* __restrict__ gram,
           float* __restrict__ sqq, float* __restrict__ sqk)
{
  __shared__ __align__(16) _Float16 xs[HSLOTS * 64];   // 30720 B
  __shared__ __align__(16) _Float16 ys[64 * HSLOTS];   // 30720 B (reused as ks[64][128])
  __shared__ __align__(16) _Float16 qs[64 * 128];      // 16384 B

  const int tid = threadIdx.x;
  const int lane = tid & 63;
  const int wid = tid >> 6;            // 0..7
  const int tile = blockIdx.x;
  const int br = blockIdx.y;
  const int b = blockIdx.z;
  const int tx0 = (tile & 15) * TW;
  const int ty0 = (tile >> 4) * TH;

  const float* wqkv = br ? wqkv2 : wqkv1;
  const float* wdw  = br ? wdw2 : wdw1;
  const float* xb = x + ((size_t)b * 128 + br * 64) * NPIX;

  // ---- stage x halo tile, f32 -> f16, transposed [px][c] with swizzle ----
  for (int u = tid; u < 32 * HSLOTS; u += 512) {
    int cp = u / HSLOTS, px = u - cp * HSLOTS;
    int hy = px / HSTR, hx = px - hy * HSTR;
    int gy = ty0 - 1 + hy, gx = tx0 - 1 + hx;
    float a0 = 0.f, a1 = 0.f;
    if (hx < 18 && (unsigned)gy < HIMG && (unsigned)gx < WIMG) {
      const float* pp = xb + (size_t)(cp * 2) * NPIX + gy * WIMG + gx;
      a0 = pp[0]; a1 = pp[NPIX];
    }
    *(__half2*)(xs + xs_idx(px, cp * 2)) = __floats2half2_rn(a0, a1);
  }
  __syncthreads();

  // parts: p=0 -> v (w part 2), p=1 -> q (w part 0), p=2 -> k (w part 1)
  for (int p = 0; p < 3; ++p) {
    const int pw = (p == 0) ? 2 : (p - 1);
    if (p) __syncthreads();

    // ---- w B-fragments into registers (global, L2-resident) ----
    half8 wf[2][4];
    #pragma unroll
    for (int nt = 0; nt < 4; ++nt)
      #pragma unroll
      for (int kc = 0; kc < 2; ++kc) {
        const float* wr = wqkv + (size_t)(pw * 64 + nt * 16 + (lane & 15)) * 64
                                 + kc * 32 + (lane >> 4) * 8;
        float4 wa = *(const float4*)wr;
        float4 wb4 = *(const float4*)(wr + 4);
        half8 h;
        h[0] = (_Float16)wa.x;  h[1] = (_Float16)wa.y;
        h[2] = (_Float16)wa.z;  h[3] = (_Float16)wa.w;
        h[4] = (_Float16)wb4.x; h[5] = (_Float16)wb4.y;
        h[6] = (_Float16)wb4.z; h[7] = (_Float16)wb4.w;
        wf[kc][nt] = h;
      }

    // ---- pointwise via MFMA: y[o][px] = sum_c w[o][c] * x[px][c] ----
    for (int mt = wid; mt < MT_N; mt += 8) {
      int px = mt * 16 + (lane & 15);
      half8 af0 = *(const half8*)(xs + px * 64 + ((((lane >> 4)    ) ^ (px & 7)) << 3));
      half8 af1 = *(const half8*)(xs + px * 64 + (((4 + (lane >> 4)) ^ (px & 7)) << 3));
      f32x4 acc[4] = {{0,0,0,0},{0,0,0,0},{0,0,0,0},{0,0,0,0}};
      #pragma unroll
      for (int nt = 0; nt < 4; ++nt) {
        acc[nt] = __builtin_amdgcn_mfma_f32_16x16x32_f16(af0, wf[0][nt], acc[nt], 0, 0, 0);
        acc[nt] = __builtin_amdgcn_mfma_f32_16x16x32_f16(af1, wf[1][nt], acc[nt], 0, 0, 0);
      }
      int pxd = mt * 16 + (lane >> 4) * 4;
      #pragma unroll
      for (int nt = 0; nt < 4; ++nt) {
        int o = nt * 16 + (lane & 15);
        __half2* dst = (__half2*)(ys + o * HSLOTS + pxd);
        dst[0] = __floats2half2_rn(acc[nt][0], acc[nt][1]);
        dst[1] = __floats2half2_rn(acc[nt][2], acc[nt][3]);
      }
    }
    __syncthreads();

    // ---- depthwise 3x3, packed half2, 16 px per thread ----
    __half2 dacc[8];
    {
      int o = tid >> 3, row = tid & 7;
      const float* wdp = wdw + (size_t)(pw * 64 + o) * 9;
      __half2 w2[9];
      #pragma unroll
      for (int j = 0; j < 9; ++j) w2[j] = __half2half2(__float2half(wdp[j]));
      #pragma unroll
      for (int k2 = 0; k2 < 8; ++k2) dacc[k2] = u2h(0u);
      #pragma unroll
      for (int ky = 0; ky < 3; ++ky) {
        const _Float16* rp = ys + o * HSLOTS + (row + ky) * HSTR;
        uint4 ra = *(const uint4*)rp;
        uint4 rb = *(const uint4*)(rp + 8);
        unsigned int rc = *(const unsigned int*)(rp + 16);
        unsigned int A[9] = {ra.x, ra.y, ra.z, ra.w, rb.x, rb.y, rb.z, rb.w, rc};
        #pragma unroll
        for (int k2 = 0; k2 < 8; ++k2) {
          unsigned int M = (A[k2] >> 16) | (A[k2 + 1] << 16);
          dacc[k2] = __hfma2(w2[ky * 3 + 0], u2h(A[k2]), dacc[k2]);
          dacc[k2] = __hfma2(w2[ky * 3 + 1], u2h(M), dacc[k2]);
          dacc[k2] = __hfma2(w2[ky * 3 + 2], u2h(A[k2 + 1]), dacc[k2]);
        }
      }
    }

    if (p == 0) {
      // v -> global (fp16)
      int o = tid >> 3, row = tid & 7;
      __half* vrow = (__half*)(vbuf + ((size_t)((br * 4 + b) * 64 + o)) * NPIX
                               + (ty0 + row) * WIMG + tx0);
      uint4 s0 = {h2u(dacc[0]), h2u(dacc[1]), h2u(dacc[2]), h2u(dacc[3])};
      uint4 s1 = {h2u(dacc[4]), h2u(dacc[5]), h2u(dacc[6]), h2u(dacc[7])};
      *(uint4*)vrow = s0;
      *(uint4*)(vrow + 8) = s1;
    } else {
      _Float16* dst = (p == 1) ? qs : ys;   // ks reuses ys region
      float* sq = (p == 1) ? sqq : sqk;
      if (p == 2) __syncthreads();          // all ys reads done before overwrite
      int o = tid >> 3, row = tid & 7;
      uint4 s0 = {h2u(dacc[0]), h2u(dacc[1]), h2u(dacc[2]), h2u(dacc[3])};
      uint4 s1 = {h2u(dacc[4]), h2u(dacc[5]), h2u(dacc[6]), h2u(dacc[7])};
      *(uint4*)(dst + qk_idx(o, 2 * row))     = s0;
      *(uint4*)(dst + qk_idx(o, 2 * row + 1)) = s1;
      float s = 0.f;
      #pragma unroll
      for (int k2 = 0; k2 < 8; ++k2) {
        float2 f = __half22float2(dacc[k2]);
        s += f.x * f.x + f.y * f.y;
      }
      s += __shfl_xor(s, 1); s += __shfl_xor(s, 2); s += __shfl_xor(s, 4);
      if ((tid & 7) == 0) atomicAdd(&sq[(br * 4 + b) * 64 + o], s);

      if (p == 2) {
        __syncthreads();
        // ---- gram: diag head-tiles via MFMA; K split across wave pairs ----
        const _Float16* ksb = ys;
        f32x4 g = {0, 0, 0, 0};
        int ch = (wid & 3) * 16 + (lane & 15);
        int kcb = (wid >> 2) * 2;
        #pragma unroll
        for (int i = 0; i < 2; ++i) {
          int pb = (kcb + i) * 4 + (lane >> 4);
          half8 aq = *(const half8*)(qs  + qk_idx(ch, pb));
          half8 bk = *(const half8*)(ksb + qk_idx(ch, pb));
          g = __builtin_amdgcn_mfma_f32_16x16x32_f16(aq, bk, g, 0, 0, 0);
        }
        if (((lane >> 3) & 1) == (lane >> 5)) {
          float* gb = gram + (br * 4 + b) * 512;
          int kch = ch;
          int qc0 = (wid & 3) * 16 + (lane >> 4) * 4;
          #pragma unroll
          for (int r = 0; r < 4; ++r) {
            int qch = qc0 + r;
            atomicAdd(&gb[(qch >> 3) * 64 + (qch & 7) * 8 + (kch & 7)], g[r]);
          }
        }
      }
    }
  }
}

// softmax(G scaled) -> attn, Weff = w_po @ blockdiag(attn), stored transposed [c'][o]
__global__ __launch_bounds__(64)
void k_attn(const float* __restrict__ gram, const float* __restrict__ sqq,
            const float* __restrict__ sqk,
            const float* __restrict__ wpo1, const float* __restrict__ wpo2,
            const float* __restrict__ t1, const float* __restrict__ t2,
            float* __restrict__ weff)
{
  const int br = blockIdx.x, b = blockIdx.y;
  const int t = threadIdx.x;
  __shared__ float attn[8][8][8];
  const float* gb = gram + (br * 4 + b) * 512;
  const float* sq = sqq + (br * 4 + b) * 64;
  const float* sk = sqk + (br * 4 + b) * 64;
  const float* tt = br ? t2 : t1;
  {
    int h = t >> 3, cq = t & 7;
    float ts = tt[h];
    float qn = fmaxf(sqrtf(sq[h * 8 + cq]), 1e-12f);
    float lg[8], m = -1e30f;
    #pragma unroll
    for (int d2 = 0; d2 < 8; ++d2) {
      float kn = fmaxf(sqrtf(sk[h * 8 + d2]), 1e-12f);
      lg[d2] = ts * gb[h * 64 + cq * 8 + d2] / (qn * kn);
      m = fmaxf(m, lg[d2]);
    }
    float s = 0.f;
    #pragma unroll
    for (int d2 = 0; d2 < 8; ++d2) { lg[d2] = expf(lg[d2] - m); s += lg[d2]; }
    float inv = 1.0f / s;
    #pragma unroll
    for (int d2 = 0; d2 < 8; ++d2) attn[h][cq][d2] = lg[d2] * inv;
  }
  __syncthreads();
  const float* wpo = br ? wpo2 : wpo1;
  float* wb = weff + (br * 4 + b) * 4096;
  for (int cp = 0; cp < 64; ++cp) {
    int hp = cp >> 3, ip = cp & 7;
    float acc = 0.f;
    #pragma unroll
    for (int j = 0; j < 8; ++j)
      acc += wpo[t * 64 + hp * 8 + j] * attn[hp][j][ip];
    wb[cp * 64 + t] = acc;   // [c'][o]
  }
}

// out[b, obr*64+o, px] = sum_c Weff[obr][b][c][o] * v[1-obr][b][c][px]
// W read via uniform address -> SGPR broadcast (no LDS)
__global__ __launch_bounds__(256)
void k_out(const __half* __restrict__ vbuf, const float* __restrict__ weff,
           float* __restrict__ out)
{
  const int obr = blockIdx.y, b = blockIdx.z;
  const int px = blockIdx.x * 256 + threadIdx.x;
  const float* wb = weff + (obr * 4 + b) * 4096;   // [c][o]
  const __half* vp = vbuf + ((size_t)((1 - obr) * 4 + b) * 64) * NPIX + px;
  float acc[64];
  #pragma unroll
  for (int o = 0; o < 64; ++o) acc[o] = 0.0f;
  for (int c = 0; c < 64; ++c) {
    float vc = __half2float(vp[(size_t)c * NPIX]);
    const float* wr = wb + c * 64;   // block-uniform -> s_load
    #pragma unroll
    for (int o = 0; o < 64; ++o) acc[o] = fmaf(wr[o], vc, acc[o]);
  }
  float* op = out + ((size_t)b * 128 + obr * 64) * NPIX + px;
  #pragma unroll
  for (int o = 0; o < 64; ++o) op[(size_t)o * NPIX] = acc[o];
}

extern "C" void kernel_launch(void* const* d_in, const int* in_sizes, int n_in,
                              void* d_out, int out_size, void* d_ws, size_t ws_size,
                              hipStream_t stream) {
  const float* x     = (const float*)d_in[0];
  const float* wqkv1 = (const float*)d_in[1];
  const float* wqkv2 = (const float*)d_in[2];
  const float* wdw1  = (const float*)d_in[3];
  const float* wdw2  = (const float*)d_in[4];
  const float* wpo1  = (const float*)d_in[5];
  const float* wpo2  = (const float*)d_in[6];
  const float* t1    = (const float*)d_in[7];
  const float* t2    = (const float*)d_in[8];

  char* ws = (char*)d_ws;
  __half* vbuf = (__half*)ws;                     // 67,108,864 B
  float* gram = (float*)(ws + 67108864);          // [2][4][8][8][8]
  float* sqq  = gram + 4096;
  float* sqk  = sqq + 512;
  float* weff = sqk + 512;                        // [2][4][64][64]

  k_zero<<<dim3(20), dim3(256), 0, stream>>>(gram, 5120);
  k_qkv<<<dim3(512, 2, 4), dim3(512), 0, stream>>>(x, wqkv1, wqkv2, wdw1, wdw2,
                                                   vbuf, gram, sqq, sqk);
  k_attn<<<dim3(2, 4), dim3(64), 0, stream>>>(gram, sqq, sqk, wpo1, wpo2, t1, t2, weff);
  k_out<<<dim3(256, 2, 4), dim3(256), 0, stream>>>(vbuf, weff, (float*)d_out);
}

// Round 5
// 299.669 us; speedup vs baseline: 1.7418x; 1.7418x over previous
//
#include <hip/hip_runtime.h>
#include <hip/hip_fp16.h>

#define NPIX 65536
#define WIMG 256
#define HIMG 256
#define TW 16
#define TH 8
#define HSTR 24      // halo row stride within a channel-plane (halves)
#define NSLOT 240    // 10 rows * 24
#define YCH 248      // ys per-channel stride (halves) — bank-balanced for DW reads
#define MT_N 15      // m-tiles of 16 px over 240 slots

typedef __attribute__((ext_vector_type(8))) _Float16 half8;
typedef __attribute__((ext_vector_type(4))) float f32x4;

__device__ __forceinline__ unsigned int h2u(__half2 h) {
  union { __half2 h; unsigned int u; } c; c.h = h; return c.u;
}
__device__ __forceinline__ __half2 u2h(unsigned int u) {
  union { unsigned int u; __half2 h; } c; c.u = u; return c.h;
}
// qs/ks layout: [ch][px 0..127] swizzled; pxblk = px>>3; returns half-index of 8-px block
__device__ __forceinline__ int qk_idx(int ch, int pxblk) {
  return ch * 128 + ((pxblk ^ (ch & 7)) << 3);
}
__device__ __forceinline__ void ld16_lds(const void* g, void* l) {
  __builtin_amdgcn_global_load_lds(
      (const __attribute__((address_space(1))) unsigned int*)g,
      (__attribute__((address_space(3))) unsigned int*)l, 16, 0, 0);
}

__global__ void k_zero(float* __restrict__ p, int n) {
  int i = blockIdx.x * 256 + threadIdx.x;
  if (i < n) p[i] = 0.0f;
}

// x f32 [b][128c][px] -> xT fp16 [b*2+br][px][c64]  (plain layout, no swizzle)
__global__ __launch_bounds__(256)
void k_xt(const float* __restrict__ x, __half* __restrict__ xT) {
  __shared__ _Float16 tile[64 * 257];     // [c][px], stride 257 halves
  const int strip = blockIdx.x;           // 256 px per strip
  const int br = blockIdx.y, b = blockIdx.z;
  const int tid = threadIdx.x;
  const float* xb = x + ((size_t)b * 128 + br * 64) * NPIX + strip * 256;
  #pragma unroll 8
  for (int c = 0; c < 64; ++c)
    tile[c * 257 + tid] = (_Float16)xb[(size_t)c * NPIX + tid];
  __syncthreads();
  __half* xo = xT + ((size_t)(b * 2 + br) * NPIX + strip * 256) * 64;
  const int j = tid & 7;
  #pragma unroll
  for (int i = 0; i < 8; ++i) {
    int p = (tid >> 3) + i * 32;
    half8 h;
    #pragma unroll
    for (int k = 0; k < 8; ++k) h[k] = tile[(j * 8 + k) * 257 + p];
    *(half8*)((_Float16*)xo + p * 64 + j * 8) = h;
  }
}

__global__ __launch_bounds__(256, 2)
void k_qkv(const __half* __restrict__ xT,
           const float* __restrict__ wqkv1, const float* __restrict__ wqkv2,
           const float* __restrict__ wdw1, const float* __restrict__ wdw2,
           const float* __restrict__ zpage,
           __half* __restrict__ vbuf, float* __restrict__ gram,
           float* __restrict__ sqq, float* __restrict__ sqk)
{
  __shared__ __align__(16) _Float16 xs[256 * 64];   // 32768 B  [slot][c] chunk-swizzled
  __shared__ __align__(16) _Float16 ys[64 * YCH];   // 31744 B  (reused as ks[64][128])
  __shared__ __align__(16) _Float16 qs[64 * 128];   // 16384 B

  const int tid = threadIdx.x;
  const int lane = tid & 63;
  const int wid = tid >> 6;
  const int tile = blockIdx.x;
  const int br = blockIdx.y;
  const int b = blockIdx.z;
  const int tx0 = (tile & 15) * TW;
  const int ty0 = (tile >> 4) * TH;

  const float* wqkv = br ? wqkv2 : wqkv1;
  const float* wdw  = br ? wdw2 : wdw1;
  const __half* xTimg = xT + (size_t)(b * 2 + br) * NPIX * 64;

  // ---- async DMA staging: 32 x 1KB, source-swizzled, LDS linear ----
  {
    const int j = lane & 7, pl = lane >> 3;
    for (int it = wid; it < 32; it += 4) {
      int s = it * 8;                 // wave-uniform slot base
      int slot = s + pl;
      int hy = slot / HSTR;
      int hx = slot - hy * HSTR;
      int gy = ty0 - 1 + hy, gx = tx0 - 1 + hx;
      bool valid = (hx < 18) && ((unsigned)gy < HIMG) && ((unsigned)gx < WIMG)
                   && (slot < NSLOT);
      const void* src = valid
        ? (const void*)((const _Float16*)xTimg + (size_t)(gy * WIMG + gx) * 64
                        + ((j ^ (slot & 7)) << 3))
        : (const void*)((const char*)zpage + lane * 16);
      ld16_lds(src, (void*)(xs + s * 64));
    }
  }
  asm volatile("s_waitcnt vmcnt(0)" ::: "memory");
  __syncthreads();

  // parts: p=0 -> v (w part 2), p=1 -> q (w part 0), p=2 -> k (w part 1)
  for (int p = 0; p < 3; ++p) {
    const int pw = (p == 0) ? 2 : (p - 1);
    if (p) __syncthreads();

    // ---- w B-fragments into registers (global, L2-resident) ----
    half8 wf[2][4];
    #pragma unroll
    for (int nt = 0; nt < 4; ++nt)
      #pragma unroll
      for (int kc = 0; kc < 2; ++kc) {
        const float* wr = wqkv + (size_t)(pw * 64 + nt * 16 + (lane & 15)) * 64
                                 + kc * 32 + (lane >> 4) * 8;
        float4 wa = *(const float4*)wr;
        float4 wb4 = *(const float4*)(wr + 4);
        half8 h;
        h[0] = (_Float16)wa.x;  h[1] = (_Float16)wa.y;
        h[2] = (_Float16)wa.z;  h[3] = (_Float16)wa.w;
        h[4] = (_Float16)wb4.x; h[5] = (_Float16)wb4.y;
        h[6] = (_Float16)wb4.z; h[7] = (_Float16)wb4.w;
        wf[kc][nt] = h;
      }

    // ---- pointwise via MFMA: y[o][px] = sum_c w[o][c] * x[px][c] ----
    for (int mt = wid; mt < MT_N; mt += 4) {
      int px = mt * 16 + (lane & 15);
      half8 af0 = *(const half8*)(xs + px * 64 + ((((lane >> 4)    ) ^ (px & 7)) << 3));
      half8 af1 = *(const half8*)(xs + px * 64 + (((4 + (lane >> 4)) ^ (px & 7)) << 3));
      f32x4 acc[4] = {{0,0,0,0},{0,0,0,0},{0,0,0,0},{0,0,0,0}};
      #pragma unroll
      for (int nt = 0; nt < 4; ++nt) {
        acc[nt] = __builtin_amdgcn_mfma_f32_16x16x32_f16(af0, wf[0][nt], acc[nt], 0, 0, 0);
        acc[nt] = __builtin_amdgcn_mfma_f32_16x16x32_f16(af1, wf[1][nt], acc[nt], 0, 0, 0);
      }
      int pxd = mt * 16 + (lane >> 4) * 4;
      #pragma unroll
      for (int nt = 0; nt < 4; ++nt) {
        int o = nt * 16 + (lane & 15);
        __half2* dst = (__half2*)(ys + o * YCH + pxd);
        dst[0] = __floats2half2_rn(acc[nt][0], acc[nt][1]);
        dst[1] = __floats2half2_rn(acc[nt][2], acc[nt][3]);
      }
    }
    __syncthreads();

    // ---- depthwise 3x3, packed half2, 2 units x 16 px per thread ----
    __half2 dacc[2][8];
    #pragma unroll
    for (int uu = 0; uu < 2; ++uu) {
      int u = tid + uu * 256;
      int o = u >> 3, row = u & 7;
      const float* wdp = wdw + (size_t)(pw * 64 + o) * 9;
      __half2 w2[9];
      #pragma unroll
      for (int j = 0; j < 9; ++j) w2[j] = __half2half2(__float2half(wdp[j]));
      __half2 a[8];
      #pragma unroll
      for (int k2 = 0; k2 < 8; ++k2) a[k2] = u2h(0u);
      #pragma unroll
      for (int ky = 0; ky < 3; ++ky) {
        const _Float16* rp = ys + o * YCH + (row + ky) * HSTR;
        uint4 ra = *(const uint4*)rp;
        uint4 rb = *(const uint4*)(rp + 8);
        unsigned int rc = *(const unsigned int*)(rp + 16);
        unsigned int A[9] = {ra.x, ra.y, ra.z, ra.w, rb.x, rb.y, rb.z, rb.w, rc};
        #pragma unroll
        for (int k2 = 0; k2 < 8; ++k2) {
          unsigned int M = (A[k2] >> 16) | (A[k2 + 1] << 16);
          a[k2] = __hfma2(w2[ky * 3 + 0], u2h(A[k2]), a[k2]);
          a[k2] = __hfma2(w2[ky * 3 + 1], u2h(M), a[k2]);
          a[k2] = __hfma2(w2[ky * 3 + 2], u2h(A[k2 + 1]), a[k2]);
        }
      }
      #pragma unroll
      for (int k2 = 0; k2 < 8; ++k2) dacc[uu][k2] = a[k2];
    }

    if (p == 0) {
      #pragma unroll
      for (int uu = 0; uu < 2; ++uu) {
        int u = tid + uu * 256;
        int o = u >> 3, row = u & 7;
        __half* vrow = (__half*)(vbuf + ((size_t)((br * 4 + b) * 64 + o)) * NPIX
                                 + (ty0 + row) * WIMG + tx0);
        uint4 s0 = {h2u(dacc[uu][0]), h2u(dacc[uu][1]), h2u(dacc[uu][2]), h2u(dacc[uu][3])};
        uint4 s1 = {h2u(dacc[uu][4]), h2u(dacc[uu][5]), h2u(dacc[uu][6]), h2u(dacc[uu][7])};
        *(uint4*)vrow = s0;
        *(uint4*)(vrow + 8) = s1;
      }
    } else {
      _Float16* dst = (p == 1) ? qs : ys;   // ks reuses ys region
      float* sq = (p == 1) ? sqq : sqk;
      if (p == 2) __syncthreads();          // all ys reads done before overwrite
      #pragma unroll
      for (int uu = 0; uu < 2; ++uu) {
        int u = tid + uu * 256;
        int o = u >> 3, row = u & 7;
        uint4 s0 = {h2u(dacc[uu][0]), h2u(dacc[uu][1]), h2u(dacc[uu][2]), h2u(dacc[uu][3])};
        uint4 s1 = {h2u(dacc[uu][4]), h2u(dacc[uu][5]), h2u(dacc[uu][6]), h2u(dacc[uu][7])};
        *(uint4*)(dst + qk_idx(o, 2 * row))     = s0;
        *(uint4*)(dst + qk_idx(o, 2 * row + 1)) = s1;
        float s = 0.f;
        #pragma unroll
        for (int k2 = 0; k2 < 8; ++k2) {
          float2 f = __half22float2(dacc[uu][k2]);
          s += f.x * f.x + f.y * f.y;
        }
        s += __shfl_xor(s, 1); s += __shfl_xor(s, 2); s += __shfl_xor(s, 4);
        if ((tid & 7) == 0) atomicAdd(&sq[(br * 4 + b) * 64 + o], s);
      }
      if (p == 2) {
        __syncthreads();
        // ---- gram: diag head-tiles via MFMA, K=128 px ----
        const _Float16* ksb = ys;
        f32x4 g = {0, 0, 0, 0};
        int ch = wid * 16 + (lane & 15);
        #pragma unroll
        for (int kc = 0; kc < 4; ++kc) {
          int pb = kc * 4 + (lane >> 4);
          half8 aq = *(const half8*)(qs  + qk_idx(ch, pb));
          half8 bk = *(const half8*)(ksb + qk_idx(ch, pb));
          g = __builtin_amdgcn_mfma_f32_16x16x32_f16(aq, bk, g, 0, 0, 0);
        }
        if (((lane >> 3) & 1) == (lane >> 5)) {
          float* gb = gram + (br * 4 + b) * 512;
          int kch = ch;
          int qc0 = wid * 16 + (lane >> 4) * 4;
          #pragma unroll
          for (int r = 0; r < 4; ++r) {
            int qch = qc0 + r;
            atomicAdd(&gb[(qch >> 3) * 64 + (qch & 7) * 8 + (kch & 7)], g[r]);
          }
        }
      }
    }
  }
}

// softmax(G scaled) -> attn, Weff = w_po @ blockdiag(attn), stored transposed [c'][o]
__global__ __launch_bounds__(64)
void k_attn(const float* __restrict__ gram, const float* __restrict__ sqq,
            const float* __restrict__ sqk,
            const float* __restrict__ wpo1, const float* __restrict__ wpo2,
            const float* __restrict__ t1, const float* __restrict__ t2,
            float* __restrict__ weff)
{
  const int br = blockIdx.x, b = blockIdx.y;
  const int t = threadIdx.x;
  __shared__ float attn[8][8][8];
  const float* gb = gram + (br * 4 + b) * 512;
  const float* sq = sqq + (br * 4 + b) * 64;
  const float* sk = sqk + (br * 4 + b) * 64;
  const float* tt = br ? t2 : t1;
  {
    int h = t >> 3, cq = t & 7;
    float ts = tt[h];
    float qn = fmaxf(sqrtf(sq[h * 8 + cq]), 1e-12f);
    float lg[8], m = -1e30f;
    #pragma unroll
    for (int d2 = 0; d2 < 8; ++d2) {
      float kn = fmaxf(sqrtf(sk[h * 8 + d2]), 1e-12f);
      lg[d2] = ts * gb[h * 64 + cq * 8 + d2] / (qn * kn);
      m = fmaxf(m, lg[d2]);
    }
    float s = 0.f;
    #pragma unroll
    for (int d2 = 0; d2 < 8; ++d2) { lg[d2] = expf(lg[d2] - m); s += lg[d2]; }
    float inv = 1.0f / s;
    #pragma unroll
    for (int d2 = 0; d2 < 8; ++d2) attn[h][cq][d2] = lg[d2] * inv;
  }
  __syncthreads();
  const float* wpo = br ? wpo2 : wpo1;
  float* wb = weff + (br * 4 + b) * 4096;
  for (int cp = 0; cp < 64; ++cp) {
    int hp = cp >> 3, ip = cp & 7;
    float acc = 0.f;
    #pragma unroll
    for (int j = 0; j < 8; ++j)
      acc += wpo[t * 64 + hp * 8 + j] * attn[hp][j][ip];
    wb[cp * 64 + t] = acc;   // [c'][o]
  }
}

// out[b, obr*64+o, px] = sum_c Weff[obr][b][c][o] * v[1-obr][b][c][px]
__global__ __launch_bounds__(256)
void k_out(const __half* __restrict__ vbuf, const float* __restrict__ weff,
           float* __restrict__ out)
{
  const int obr = blockIdx.y, b = blockIdx.z;
  const int px = blockIdx.x * 256 + threadIdx.x;
  const float* wb = weff + (obr * 4 + b) * 4096;   // [c][o]
  const __half* vp = vbuf + ((size_t)((1 - obr) * 4 + b) * 64) * NPIX + px;
  float acc[64];
  #pragma unroll
  for (int o = 0; o < 64; ++o) acc[o] = 0.0f;
  for (int c = 0; c < 64; ++c) {
    float vc = __half2float(vp[(size_t)c * NPIX]);
    const float* wr = wb + c * 64;   // block-uniform -> s_load
    #pragma unroll
    for (int o = 0; o < 64; ++o) acc[o] = fmaf(wr[o], vc, acc[o]);
  }
  float* op = out + ((size_t)b * 128 + obr * 64) * NPIX + px;
  #pragma unroll
  for (int o = 0; o < 64; ++o) op[(size_t)o * NPIX] = acc[o];
}

extern "C" void kernel_launch(void* const* d_in, const int* in_sizes, int n_in,
                              void* d_out, int out_size, void* d_ws, size_t ws_size,
                              hipStream_t stream) {
  const float* x     = (const float*)d_in[0];
  const float* wqkv1 = (const float*)d_in[1];
  const float* wqkv2 = (const float*)d_in[2];
  const float* wdw1  = (const float*)d_in[3];
  const float* wdw2  = (const float*)d_in[4];
  const float* wpo1  = (const float*)d_in[5];
  const float* wpo2  = (const float*)d_in[6];
  const float* t1    = (const float*)d_in[7];
  const float* t2    = (const float*)d_in[8];

  char* ws = (char*)d_ws;
  __half* vbuf = (__half*)ws;                     // 67,108,864 B
  float* gram  = (float*)(ws + 67108864);         // 4096 f32
  float* sqq   = gram + 4096;                     // 512
  float* sqk   = sqq + 512;                       // 512
  float* zpage = sqk + 512;                       // 1024 f32 (zeros for OOB DMA)
  float* weff  = zpage + 1024;                    // 32768 f32

  // xT lives in the (not-yet-written) first 67 MB of d_out
  __half* xT = (__half*)d_out;

  k_zero<<<dim3(24), dim3(256), 0, stream>>>(gram, 6144);
  k_xt<<<dim3(256, 2, 4), dim3(256), 0, stream>>>(x, xT);
  k_qkv<<<dim3(512, 2, 4), dim3(256), 0, stream>>>(xT, wqkv1, wqkv2, wdw1, wdw2,
                                                   zpage, vbuf, gram, sqq, sqk);
  k_attn<<<dim3(2, 4), dim3(64), 0, stream>>>(gram, sqq, sqk, wpo1, wpo2, t1, t2, weff);
  k_out<<<dim3(256, 2, 4), dim3(256), 0, stream>>>(vbuf, weff, (float*)d_out);
}